// Round 2
// baseline (290.387 us; speedup 1.0000x reference)
//
#include <hip/hip_runtime.h>
#include <cstdint>

#define TS 8192      // tokens (S)
#define TD 4096      // model dim (D)
#define TE 64        // experts (E)
#define TCAP 128     // capacity

static constexpr size_t SEC = (size_t)TS * TE * TCAP;  // 67,108,864

// ---------------------------------------------------------------------------
// Kernel 0: full-occupancy zero fill of the output buffer.
// Replaces hipMemsetAsync's rocclr fill (which ran at 10% occupancy /
// ~1.7 TB/s). Grid-stride float4 stores; thread (0,0) also zeroes the one
// trailing scalar element (out_size = 2*SEC + 65 = 4*N + 1).
// ---------------------------------------------------------------------------
__global__ __launch_bounds__(256) void zero_fill(
    float4* __restrict__ out4, float* __restrict__ out, long nvec)
{
    const long stride = (long)gridDim.x * blockDim.x;
    const float4 z = make_float4(0.f, 0.f, 0.f, 0.f);
    for (long i = (long)blockIdx.x * blockDim.x + threadIdx.x; i < nvec; i += stride)
        out4[i] = z;
    if (blockIdx.x == 0 && threadIdx.x == 0)
        out[nvec * 4] = 0.f;   // trailing element (out_size % 4 == 1)
}

// ---------------------------------------------------------------------------
// Kernel 1: logits GEMM (x[S,D] · wg[E,D]^T) + row softmax + argmax, fused.
// 256 blocks x 256 threads; each block: 32 tokens x 64 experts.
// ---------------------------------------------------------------------------
__global__ __launch_bounds__(256) void gate_gemm_softmax(
    const float* __restrict__ x, const float* __restrict__ wg,
    int* __restrict__ eidx, float* __restrict__ gtop,
    float* __restrict__ partial_me)
{
    __shared__ float xs[64][34];   // [k][token]
    __shared__ float wsh[64][68];  // [k][expert]
    __shared__ float cs[4][64];

    const int tid = threadIdx.x;
    const int tx = tid & 15;   // expert group (4 experts)
    const int ty = tid >> 4;   // token group  (2 tokens)
    const int tok0 = blockIdx.x * 32;

    float acc[2][4] = {{0.f,0.f,0.f,0.f},{0.f,0.f,0.f,0.f}};

    for (int d0 = 0; d0 < TD; d0 += 64) {
        #pragma unroll
        for (int r = 0; r < 2; ++r) {
            const int t = r * 16 + ty;
            const float4 v = *reinterpret_cast<const float4*>(
                &x[(size_t)(tok0 + t) * TD + d0 + tx * 4]);
            xs[tx*4+0][t] = v.x; xs[tx*4+1][t] = v.y;
            xs[tx*4+2][t] = v.z; xs[tx*4+3][t] = v.w;
        }
        #pragma unroll
        for (int r = 0; r < 4; ++r) {
            const int e = r * 16 + ty;
            const float4 v = *reinterpret_cast<const float4*>(
                &wg[(size_t)e * TD + d0 + tx * 4]);
            wsh[tx*4+0][e] = v.x; wsh[tx*4+1][e] = v.y;
            wsh[tx*4+2][e] = v.z; wsh[tx*4+3][e] = v.w;
        }
        __syncthreads();
        #pragma unroll
        for (int k = 0; k < 64; ++k) {
            const float2 a = *reinterpret_cast<const float2*>(&xs[k][ty*2]);
            const float4 b = *reinterpret_cast<const float4*>(&wsh[k][tx*4]);
            acc[0][0] = fmaf(a.x, b.x, acc[0][0]);
            acc[0][1] = fmaf(a.x, b.y, acc[0][1]);
            acc[0][2] = fmaf(a.x, b.z, acc[0][2]);
            acc[0][3] = fmaf(a.x, b.w, acc[0][3]);
            acc[1][0] = fmaf(a.y, b.x, acc[1][0]);
            acc[1][1] = fmaf(a.y, b.y, acc[1][1]);
            acc[1][2] = fmaf(a.y, b.z, acc[1][2]);
            acc[1][3] = fmaf(a.y, b.w, acc[1][3]);
        }
        __syncthreads();
    }

    // Fused softmax + argmax over each token's 64 logits (16 lanes x 4 regs).
    float colsum[4] = {0.f, 0.f, 0.f, 0.f};
    #pragma unroll
    for (int r = 0; r < 2; ++r) {
        float lm = fmaxf(fmaxf(acc[r][0], acc[r][1]), fmaxf(acc[r][2], acc[r][3]));
        #pragma unroll
        for (int mask = 1; mask <= 8; mask <<= 1)
            lm = fmaxf(lm, __shfl_xor(lm, mask));
        float p[4]; float ls = 0.f;
        #pragma unroll
        for (int j = 0; j < 4; ++j) { p[j] = __expf(acc[r][j] - lm); ls += p[j]; }
        #pragma unroll
        for (int mask = 1; mask <= 8; mask <<= 1)
            ls += __shfl_xor(ls, mask);
        const float invZ = 1.0f / ls;

        // argmax with lowest-index tie-break (matches jnp.argmax)
        float bv = acc[r][0]; int bi = tx * 4;
        #pragma unroll
        for (int j = 1; j < 4; ++j)
            if (acc[r][j] > bv) { bv = acc[r][j]; bi = tx * 4 + j; }
        #pragma unroll
        for (int mask = 1; mask <= 8; mask <<= 1) {
            const float ov = __shfl_xor(bv, mask);
            const int   oi = __shfl_xor(bi, mask);
            if (ov > bv || (ov == bv && oi < bi)) { bv = ov; bi = oi; }
        }
        if (tx == 0) {
            const int s = tok0 + ty * 2 + r;
            eidx[s] = bi;
            gtop[s] = invZ;
        }
        #pragma unroll
        for (int j = 0; j < 4; ++j) colsum[j] += p[j] * invZ;
    }

    #pragma unroll
    for (int j = 0; j < 4; ++j) {
        colsum[j] += __shfl_xor(colsum[j], 16);
        colsum[j] += __shfl_xor(colsum[j], 32);
    }
    const int wave = tid >> 6;
    const int lane = tid & 63;
    if (lane < 16) {
        #pragma unroll
        for (int j = 0; j < 4; ++j) cs[wave][lane * 4 + j] = colsum[j];
    }
    __syncthreads();
    if (tid < 64) {
        partial_me[(size_t)blockIdx.x * 64 + tid] =
            cs[0][tid] + cs[1][tid] + cs[2][tid] + cs[3][tid];
    }
}

// ---------------------------------------------------------------------------
// Kernel 2: per-expert ordered rank, capacity truncation, sparse scatter.
// ---------------------------------------------------------------------------
__global__ __launch_bounds__(256) void rank_scatter(
    const int* __restrict__ eidx, const float* __restrict__ gtop,
    float* __restrict__ out, int* __restrict__ counts)
{
    const int e = blockIdx.x;
    const int tid = threadIdx.x;
    const int wave = tid >> 6;
    const int lane = tid & 63;
    __shared__ int wave_tot[4];

    int running = 0;
    for (int s0 = 0; s0 < TS; s0 += 256) {
        const int s = s0 + tid;
        const bool m = (eidx[s] == e);
        const unsigned long long b = __ballot(m);
        if (lane == 0) wave_tot[wave] = __popcll(b);
        __syncthreads();
        int off = running;
        #pragma unroll
        for (int w = 0; w < 4; ++w) if (w < wave) off += wave_tot[w];
        const int rank = off + __popcll(b & ((1ull << lane) - 1ull));
        if (m && rank < TCAP) {
            const size_t base = 1 + ((size_t)s * TE + e) * TCAP + (size_t)rank;
            out[base] = gtop[s];        // combine_weights
            out[base + SEC] = 1.0f;     // dispatch_mask (as float)
        }
        running += wave_tot[0] + wave_tot[1] + wave_tot[2] + wave_tot[3];
        __syncthreads();
    }
    if (tid == 0) {
        counts[e] = running;
        out[1 + 2 * SEC + e] = (float)running;
    }
}

// ---------------------------------------------------------------------------
// Kernel 3: l_aux
// ---------------------------------------------------------------------------
__global__ __launch_bounds__(64) void finalize_laux(
    const float* __restrict__ partial_me, const int* __restrict__ counts,
    float* __restrict__ out)
{
    const int e = threadIdx.x;
    float s = 0.f;
    for (int b = 0; b < 256; ++b) s += partial_me[(size_t)b * 64 + e];
    const float me = s * (1.0f / TS);
    const float ce = (float)counts[e] * (1.0f / TS);
    float v = me * ce;
    #pragma unroll
    for (int mask = 32; mask >= 1; mask >>= 1) v += __shfl_xor(v, mask);
    if (e == 0) out[0] = v * (float)TE;
}

extern "C" void kernel_launch(void* const* d_in, const int* in_sizes, int n_in,
                              void* d_out, int out_size, void* d_ws, size_t ws_size,
                              hipStream_t stream) {
    const float* x  = (const float*)d_in[0];
    const float* wg = (const float*)d_in[1];
    float* out = (float*)d_out;

    int*   eidx       = (int*)d_ws;                           // TS ints
    float* gtop       = (float*)((char*)d_ws + TS * 4);       // TS floats
    float* partial_me = gtop + TS;                            // 256*64 floats
    int*   counts     = (int*)(partial_me + 256 * 64);        // TE ints

    const long nvec = (long)out_size / 4;   // out_size = 2*SEC + 65 = 4*nvec + 1
    hipLaunchKernelGGL(zero_fill, dim3(4096), dim3(256), 0, stream,
                       (float4*)out, out, nvec);
    hipLaunchKernelGGL(gate_gemm_softmax, dim3(256), dim3(256), 0, stream,
                       x, wg, eidx, gtop, partial_me);
    hipLaunchKernelGGL(rank_scatter, dim3(64), dim3(256), 0, stream,
                       eidx, gtop, out, counts);
    hipLaunchKernelGGL(finalize_laux, dim3(1), dim3(64), 0, stream,
                       partial_me, counts, out);
}

// Round 4
// 184.932 us; speedup vs baseline: 1.5702x; 1.5702x over previous
//
#include <hip/hip_runtime.h>
#include <cstdint>

#define TS 8192      // tokens (S)
#define TD 4096      // model dim (D)
#define TE 64        // experts (E)
#define TCAP 128     // capacity
#define KS 8         // K-splits
#define KB (TD/KS)   // 512 k per block
#define KC 32        // k-chunk staged in LDS
#define TB 128       // tokens per block
#define NTB (TS/TB)  // 64 token-blocks

static constexpr size_t SEC = (size_t)TS * TE * TCAP;  // 67,108,864

typedef float f32x4 __attribute__((ext_vector_type(4)));   // native vec for NT builtins

// ---------------------------------------------------------------------------
// Kernel A: fp32 logits GEMM (K-split partials) FUSED with the mandatory
// 537 MB zero-fill of the output (nontemporal stores interleaved with the
// K-loop — fill is write-BW-bound, GEMM is VALU-bound, they overlap).
// Grid 512 = 64 token-blocks x 8 K-splits; 512 threads (2 blocks/CU,
// 4 waves/SIMD). Micro-tile 4 tok x 4 exp per thread.
// Fill: 512 blocks x 65536 float4 = floats [0, 2*SEC); tail 65 by block 0.
// ---------------------------------------------------------------------------
__global__ __launch_bounds__(512, 4) void gemm_fill(
    const float* __restrict__ x, const float* __restrict__ wg,
    float* __restrict__ part, f32x4* __restrict__ out4,
    float* __restrict__ out)
{
    __shared__ float xs[KC][132];   // [k][token], stride 132: 16B-aligned rows
    __shared__ float wsh[KC][68];   // [k][expert]

    const int tid = threadIdx.x;
    const int bid = blockIdx.x;
    const int tb  = bid & (NTB - 1);
    const int ks  = bid >> 6;
    const int tok0 = tb * TB;
    const int tx = tid & 15;        // expert group: experts tx*4..+3
    const int ty = tid >> 4;        // token group:  tokens ty*4..+3 (ty 0..31)
    const int kq_s  = tid & 7;      // staging: k-quad 0..7
    const int row_s = tid >> 3;     // staging: row 0..63
    const long fill0 = (long)bid * 65536;
    const f32x4 z4 = {0.f, 0.f, 0.f, 0.f};

    float acc[4][4] = {{0,0,0,0},{0,0,0,0},{0,0,0,0},{0,0,0,0}};

    for (int it = 0; it < KB / KC; ++it) {   // 16 iterations
        const int k0 = ks * KB + it * KC;
        // stage x tile: 128 tok x 32 k, transposed -> xs[k][tok]
        #pragma unroll
        for (int r = 0; r < 2; ++r) {
            const int t = r * 64 + row_s;
            const f32x4 v = __builtin_nontemporal_load(
                reinterpret_cast<const f32x4*>(&x[(size_t)(tok0 + t) * TD + k0 + kq_s * 4]));
            xs[kq_s*4+0][t] = v.x; xs[kq_s*4+1][t] = v.y;
            xs[kq_s*4+2][t] = v.z; xs[kq_s*4+3][t] = v.w;
        }
        // stage wg tile: 64 exp x 32 k, transposed -> wsh[k][e]
        {
            const f32x4 v = *reinterpret_cast<const f32x4*>(
                &wg[(size_t)row_s * TD + k0 + kq_s * 4]);
            wsh[kq_s*4+0][row_s] = v.x; wsh[kq_s*4+1][row_s] = v.y;
            wsh[kq_s*4+2][row_s] = v.z; wsh[kq_s*4+3][row_s] = v.w;
        }
        __syncthreads();
        // interleaved zero-fill: 8 float4 per thread per iter (coalesced, NT)
        #pragma unroll
        for (int j = 0; j < 8; ++j)
            __builtin_nontemporal_store(z4, &out4[fill0 + (long)it * 4096 + j * 512 + tid]);
        // micro-kernel: 4 tok x 4 exp
        #pragma unroll
        for (int k = 0; k < KC; ++k) {
            const f32x4 a = *reinterpret_cast<const f32x4*>(&xs[k][ty * 4]);
            const f32x4 b = *reinterpret_cast<const f32x4*>(&wsh[k][tx * 4]);
            acc[0][0] = fmaf(a.x, b.x, acc[0][0]);
            acc[0][1] = fmaf(a.x, b.y, acc[0][1]);
            acc[0][2] = fmaf(a.x, b.z, acc[0][2]);
            acc[0][3] = fmaf(a.x, b.w, acc[0][3]);
            acc[1][0] = fmaf(a.y, b.x, acc[1][0]);
            acc[1][1] = fmaf(a.y, b.y, acc[1][1]);
            acc[1][2] = fmaf(a.y, b.z, acc[1][2]);
            acc[1][3] = fmaf(a.y, b.w, acc[1][3]);
            acc[2][0] = fmaf(a.z, b.x, acc[2][0]);
            acc[2][1] = fmaf(a.z, b.y, acc[2][1]);
            acc[2][2] = fmaf(a.z, b.z, acc[2][2]);
            acc[2][3] = fmaf(a.z, b.w, acc[2][3]);
            acc[3][0] = fmaf(a.w, b.x, acc[3][0]);
            acc[3][1] = fmaf(a.w, b.y, acc[3][1]);
            acc[3][2] = fmaf(a.w, b.z, acc[3][2]);
            acc[3][3] = fmaf(a.w, b.w, acc[3][3]);
        }
        __syncthreads();
    }
    // tail: floats [2*SEC, 2*SEC+64] (last dispatch elem + counts slots)
    if (bid == 0 && tid < 65) out[2 * SEC + tid] = 0.f;
    // write partial logits: part[ks][tok][exp]
    #pragma unroll
    for (int i = 0; i < 4; ++i) {
        const int t = tok0 + ty * 4 + i;
        f32x4 v;
        v.x = acc[i][0]; v.y = acc[i][1]; v.z = acc[i][2]; v.w = acc[i][3];
        *reinterpret_cast<f32x4*>(&part[((size_t)ks * TS + t) * TE + tx * 4]) = v;
    }
}

// ---------------------------------------------------------------------------
// Kernel B: reduce K-split partials + softmax + argmax per token.
// 512 blocks x 256 threads; 16 tokens/block, 16 lanes per token (4 exp each).
// ---------------------------------------------------------------------------
__global__ __launch_bounds__(256) void softmax_argmax(
    const float* __restrict__ part, int* __restrict__ eidx,
    float* __restrict__ gtop, float* __restrict__ partial_me)
{
    __shared__ float cs[4][64];
    const int tid = threadIdx.x;
    const int tx = tid & 15;
    const int ty = tid >> 4;         // token slot 0..15
    const int s = blockIdx.x * 16 + ty;

    float p[4] = {0.f, 0.f, 0.f, 0.f};
    #pragma unroll
    for (int ks = 0; ks < KS; ++ks) {
        const f32x4 v = *reinterpret_cast<const f32x4*>(
            &part[((size_t)ks * TS + s) * TE + tx * 4]);
        p[0] += v.x; p[1] += v.y; p[2] += v.z; p[3] += v.w;
    }

    // softmax over the token's 64 logits (16 lanes x 4 regs)
    float lm = fmaxf(fmaxf(p[0], p[1]), fmaxf(p[2], p[3]));
    #pragma unroll
    for (int mask = 1; mask <= 8; mask <<= 1)
        lm = fmaxf(lm, __shfl_xor(lm, mask));
    float ep[4]; float ls = 0.f;
    #pragma unroll
    for (int j = 0; j < 4; ++j) { ep[j] = __expf(p[j] - lm); ls += ep[j]; }
    #pragma unroll
    for (int mask = 1; mask <= 8; mask <<= 1)
        ls += __shfl_xor(ls, mask);
    const float invZ = 1.0f / ls;

    // argmax with lowest-index tie-break (matches jnp.argmax)
    float bv = p[0]; int bi = tx * 4;
    #pragma unroll
    for (int j = 1; j < 4; ++j)
        if (p[j] > bv) { bv = p[j]; bi = tx * 4 + j; }
    #pragma unroll
    for (int mask = 1; mask <= 8; mask <<= 1) {
        const float ov = __shfl_xor(bv, mask);
        const int   oi = __shfl_xor(bi, mask);
        if (ov > bv || (ov == bv && oi < bi)) { bv = ov; bi = oi; }
    }
    if (tx == 0) { eidx[s] = bi; gtop[s] = invZ; }

    // column sums of gates (for l_aux's me), deterministic reduction
    float colsum[4];
    #pragma unroll
    for (int j = 0; j < 4; ++j) colsum[j] = ep[j] * invZ;
    #pragma unroll
    for (int j = 0; j < 4; ++j) {
        colsum[j] += __shfl_xor(colsum[j], 16);
        colsum[j] += __shfl_xor(colsum[j], 32);
    }
    const int wave = tid >> 6;
    const int lane = tid & 63;
    if (lane < 16) {
        #pragma unroll
        for (int j = 0; j < 4; ++j) cs[wave][lane * 4 + j] = colsum[j];
    }
    __syncthreads();
    if (tid < 64) {
        partial_me[(size_t)blockIdx.x * 64 + tid] =
            cs[0][tid] + cs[1][tid] + cs[2][tid] + cs[3][tid];
    }
}

// ---------------------------------------------------------------------------
// Kernel C: per-expert ordered rank, capacity truncation, sparse scatter.
// ---------------------------------------------------------------------------
__global__ __launch_bounds__(256) void rank_scatter(
    const int* __restrict__ eidx, const float* __restrict__ gtop,
    float* __restrict__ out, int* __restrict__ counts)
{
    const int e = blockIdx.x;
    const int tid = threadIdx.x;
    const int wave = tid >> 6;
    const int lane = tid & 63;
    __shared__ int wave_tot[4];

    int running = 0;
    for (int s0 = 0; s0 < TS; s0 += 256) {
        const int s = s0 + tid;
        const bool m = (eidx[s] == e);
        const unsigned long long b = __ballot(m);
        if (lane == 0) wave_tot[wave] = __popcll(b);
        __syncthreads();
        int off = running;
        #pragma unroll
        for (int w = 0; w < 4; ++w) if (w < wave) off += wave_tot[w];
        const int rank = off + __popcll(b & ((1ull << lane) - 1ull));
        if (m && rank < TCAP) {
            const size_t base = 1 + ((size_t)s * TE + e) * TCAP + (size_t)rank;
            out[base] = gtop[s];        // combine_weights
            out[base + SEC] = 1.0f;     // dispatch_mask (as float)
        }
        running += wave_tot[0] + wave_tot[1] + wave_tot[2] + wave_tot[3];
        __syncthreads();
    }
    if (tid == 0) {
        counts[e] = running;
        out[1 + 2 * SEC + e] = (float)running;
    }
}

// ---------------------------------------------------------------------------
// Kernel D: l_aux
// ---------------------------------------------------------------------------
__global__ __launch_bounds__(64) void finalize_laux(
    const float* __restrict__ partial_me, const int* __restrict__ counts,
    float* __restrict__ out)
{
    const int e = threadIdx.x;
    float s = 0.f;
    for (int b = 0; b < 512; ++b) s += partial_me[(size_t)b * 64 + e];
    const float me = s * (1.0f / TS);
    const float ce = (float)counts[e] * (1.0f / TS);
    float v = me * ce;
    #pragma unroll
    for (int mask = 32; mask >= 1; mask >>= 1) v += __shfl_xor(v, mask);
    if (e == 0) out[0] = v * (float)TE;
}

extern "C" void kernel_launch(void* const* d_in, const int* in_sizes, int n_in,
                              void* d_out, int out_size, void* d_ws, size_t ws_size,
                              hipStream_t stream) {
    const float* x  = (const float*)d_in[0];
    const float* wg = (const float*)d_in[1];
    float* out = (float*)d_out;

    // workspace layout
    float* part       = (float*)d_ws;                        // KS*TS*TE floats (16.8 MB)
    int*   eidx       = (int*)(part + (size_t)KS * TS * TE); // TS ints
    float* gtop       = (float*)(eidx + TS);                 // TS floats
    float* partial_me = gtop + TS;                           // 512*64 floats
    int*   counts     = (int*)(partial_me + 512 * 64);       // TE ints

    hipLaunchKernelGGL(gemm_fill, dim3(512), dim3(512), 0, stream,
                       x, wg, part, (f32x4*)out, out);
    hipLaunchKernelGGL(softmax_argmax, dim3(512), dim3(256), 0, stream,
                       part, eidx, gtop, partial_me);
    hipLaunchKernelGGL(rank_scatter, dim3(64), dim3(256), 0, stream,
                       eidx, gtop, out, counts);
    hipLaunchKernelGGL(finalize_laux, dim3(1), dim3(64), 0, stream,
                       partial_me, counts, out);
}

// Round 5
// 170.249 us; speedup vs baseline: 1.7057x; 1.0862x over previous
//
#include <hip/hip_runtime.h>
#include <cstdint>

#define TS 8192      // tokens (S)
#define TD 4096      // model dim (D)
#define TE 64        // experts (E)
#define TCAP 128     // capacity
#define KS 8         // K-splits
#define KB (TD/KS)   // 512 k per block
#define KC 32        // k-chunk staged in LDS
#define TB 128       // tokens per block
#define NTB (TS/TB)  // 64 token-blocks

static constexpr size_t SEC = (size_t)TS * TE * TCAP;  // 67,108,864

typedef float f32x4 __attribute__((ext_vector_type(4)));   // native vec for NT builtins

// ---------------------------------------------------------------------------
// Kernel A: fp32 logits GEMM (K-split partials) FUSED with the mandatory
// 537 MB zero-fill (NT stores spread through the FMA k-loop).
// Grid 512 = 64 token-blocks x 8 K-splits; 512 threads; 4 tok x 4 exp/thread.
// ---------------------------------------------------------------------------
__global__ __launch_bounds__(512, 4) void gemm_fill(
    const float* __restrict__ x, const float* __restrict__ wg,
    float* __restrict__ part, f32x4* __restrict__ out4,
    float* __restrict__ out)
{
    __shared__ float xs[KC][132];   // [k][token]
    __shared__ float wsh[KC][68];   // [k][expert]

    const int tid = threadIdx.x;
    const int bid = blockIdx.x;
    const int tb  = bid & (NTB - 1);
    const int ks  = bid >> 6;
    const int tok0 = tb * TB;
    const int tx = tid & 15;        // expert group: experts tx*4..+3
    const int ty = tid >> 4;        // token group:  tokens ty*4..+3
    const int kq_s  = tid & 7;      // staging: k-quad 0..7
    const int row_s = tid >> 3;     // staging: row 0..63
    const long fill0 = (long)bid * 65536;
    const f32x4 z4 = {0.f, 0.f, 0.f, 0.f};

    float acc[4][4] = {{0,0,0,0},{0,0,0,0},{0,0,0,0},{0,0,0,0}};

    for (int it = 0; it < KB / KC; ++it) {   // 16 iterations
        const int k0 = ks * KB + it * KC;
        // stage x tile: 128 tok x 32 k, transposed -> xs[k][tok]
        #pragma unroll
        for (int r = 0; r < 2; ++r) {
            const int t = r * 64 + row_s;
            const f32x4 v = __builtin_nontemporal_load(
                reinterpret_cast<const f32x4*>(&x[(size_t)(tok0 + t) * TD + k0 + kq_s * 4]));
            xs[kq_s*4+0][t] = v.x; xs[kq_s*4+1][t] = v.y;
            xs[kq_s*4+2][t] = v.z; xs[kq_s*4+3][t] = v.w;
        }
        // stage wg tile: 64 exp x 32 k, transposed -> wsh[k][e]
        {
            const f32x4 v = *reinterpret_cast<const f32x4*>(
                &wg[(size_t)row_s * TD + k0 + kq_s * 4]);
            wsh[kq_s*4+0][row_s] = v.x; wsh[kq_s*4+1][row_s] = v.y;
            wsh[kq_s*4+2][row_s] = v.z; wsh[kq_s*4+3][row_s] = v.w;
        }
        __syncthreads();
        // micro-kernel 4x4 with one NT fill store every 4 k-steps
        #pragma unroll
        for (int k = 0; k < KC; ++k) {
            if ((k & 3) == 0) {
                const int j = k >> 2;
                __builtin_nontemporal_store(z4,
                    &out4[fill0 + (long)it * 4096 + j * 512 + tid]);
            }
            const f32x4 a = *reinterpret_cast<const f32x4*>(&xs[k][ty * 4]);
            const f32x4 b = *reinterpret_cast<const f32x4*>(&wsh[k][tx * 4]);
            acc[0][0] = fmaf(a.x, b.x, acc[0][0]);
            acc[0][1] = fmaf(a.x, b.y, acc[0][1]);
            acc[0][2] = fmaf(a.x, b.z, acc[0][2]);
            acc[0][3] = fmaf(a.x, b.w, acc[0][3]);
            acc[1][0] = fmaf(a.y, b.x, acc[1][0]);
            acc[1][1] = fmaf(a.y, b.y, acc[1][1]);
            acc[1][2] = fmaf(a.y, b.z, acc[1][2]);
            acc[1][3] = fmaf(a.y, b.w, acc[1][3]);
            acc[2][0] = fmaf(a.z, b.x, acc[2][0]);
            acc[2][1] = fmaf(a.z, b.y, acc[2][1]);
            acc[2][2] = fmaf(a.z, b.z, acc[2][2]);
            acc[2][3] = fmaf(a.z, b.w, acc[2][3]);
            acc[3][0] = fmaf(a.w, b.x, acc[3][0]);
            acc[3][1] = fmaf(a.w, b.y, acc[3][1]);
            acc[3][2] = fmaf(a.w, b.z, acc[3][2]);
            acc[3][3] = fmaf(a.w, b.w, acc[3][3]);
        }
        __syncthreads();
    }
    // tail: floats [2*SEC, 2*SEC+64] (last dispatch elem + counts slots)
    if (bid == 0 && tid < 65) out[2 * SEC + tid] = 0.f;
    // write partial logits: part[ks][tok][exp]
    #pragma unroll
    for (int i = 0; i < 4; ++i) {
        const int t = tok0 + ty * 4 + i;
        f32x4 v;
        v.x = acc[i][0]; v.y = acc[i][1]; v.z = acc[i][2]; v.w = acc[i][3];
        *reinterpret_cast<f32x4*>(&part[((size_t)ks * TS + t) * TE + tx * 4]) = v;
    }
}

// ---------------------------------------------------------------------------
// Kernel B: reduce K-split partials + softmax + argmax per token.
// 512 blocks x 256 threads; 16 tokens/block, 16 lanes per token.
// ---------------------------------------------------------------------------
__global__ __launch_bounds__(256) void softmax_argmax(
    const float* __restrict__ part, int* __restrict__ eidx,
    float* __restrict__ gtop, float* __restrict__ partial_me)
{
    __shared__ float cs[4][64];
    const int tid = threadIdx.x;
    const int tx = tid & 15;
    const int ty = tid >> 4;
    const int s = blockIdx.x * 16 + ty;

    float p[4] = {0.f, 0.f, 0.f, 0.f};
    #pragma unroll
    for (int ks = 0; ks < KS; ++ks) {
        const f32x4 v = *reinterpret_cast<const f32x4*>(
            &part[((size_t)ks * TS + s) * TE + tx * 4]);
        p[0] += v.x; p[1] += v.y; p[2] += v.z; p[3] += v.w;
    }

    float lm = fmaxf(fmaxf(p[0], p[1]), fmaxf(p[2], p[3]));
    #pragma unroll
    for (int mask = 1; mask <= 8; mask <<= 1)
        lm = fmaxf(lm, __shfl_xor(lm, mask));
    float ep[4]; float ls = 0.f;
    #pragma unroll
    for (int j = 0; j < 4; ++j) { ep[j] = __expf(p[j] - lm); ls += ep[j]; }
    #pragma unroll
    for (int mask = 1; mask <= 8; mask <<= 1)
        ls += __shfl_xor(ls, mask);
    const float invZ = 1.0f / ls;

    // argmax, lowest-index tie-break
    float bv = p[0]; int bi = tx * 4;
    #pragma unroll
    for (int j = 1; j < 4; ++j)
        if (p[j] > bv) { bv = p[j]; bi = tx * 4 + j; }
    #pragma unroll
    for (int mask = 1; mask <= 8; mask <<= 1) {
        const float ov = __shfl_xor(bv, mask);
        const int   oi = __shfl_xor(bi, mask);
        if (ov > bv || (ov == bv && oi < bi)) { bv = ov; bi = oi; }
    }
    if (tx == 0) { eidx[s] = bi; gtop[s] = invZ; }

    float colsum[4];
    #pragma unroll
    for (int j = 0; j < 4; ++j) colsum[j] = ep[j] * invZ;
    #pragma unroll
    for (int j = 0; j < 4; ++j) {
        colsum[j] += __shfl_xor(colsum[j], 16);
        colsum[j] += __shfl_xor(colsum[j], 32);
    }
    const int wave = tid >> 6;
    const int lane = tid & 63;
    if (lane < 16) {
        #pragma unroll
        for (int j = 0; j < 4; ++j) cs[wave][lane * 4 + j] = colsum[j];
    }
    __syncthreads();
    if (tid < 64) {
        partial_me[(size_t)blockIdx.x * 64 + tid] =
            cs[0][tid] + cs[1][tid] + cs[2][tid] + cs[3][tid];
    }
}

// ---------------------------------------------------------------------------
// Kernel C: per-expert ordered rank + capacity + scatter + fused l_aux.
// 64 blocks x 1024 threads. All 8 token-chunks prefetched to registers,
// then 8 ballot/prefix rounds (LDS only). l_aux via one atomicAdd per block.
// ---------------------------------------------------------------------------
__global__ __launch_bounds__(1024) void rank_scatter_laux(
    const int* __restrict__ eidx, const float* __restrict__ gtop,
    const float* __restrict__ partial_me, float* __restrict__ out)
{
    const int e = blockIdx.x;
    const int tid = threadIdx.x;
    const int wave = tid >> 6;      // 0..15
    const int lane = tid & 63;
    __shared__ int wave_tot[16];
    __shared__ float red[8];

    // prefetch all 8 chunks (coalesced, issued back-to-back)
    int ev[8];
    #pragma unroll
    for (int r = 0; r < 8; ++r) ev[r] = eidx[r * 1024 + tid];

    int running = 0;
    #pragma unroll
    for (int r = 0; r < 8; ++r) {
        const bool m = (ev[r] == e);
        const unsigned long long b = __ballot(m);
        if (lane == 0) wave_tot[wave] = __popcll(b);
        __syncthreads();
        int off = running;
        #pragma unroll
        for (int w = 0; w < 16; ++w) if (w < wave) off += wave_tot[w];
        const int rank = off + __popcll(b & ((1ull << lane) - 1ull));
        if (m && rank < TCAP) {
            const int s = r * 1024 + tid;
            const size_t base = 1 + ((size_t)s * TE + e) * TCAP + (size_t)rank;
            out[base] = gtop[s];        // combine_weights
            out[base + SEC] = 1.0f;     // dispatch_mask (as float)
        }
        int tot = 0;
        #pragma unroll
        for (int w = 0; w < 16; ++w) tot += wave_tot[w];
        running += tot;
        __syncthreads();
    }
    if (tid == 0) out[1 + 2 * SEC + e] = (float)running;   // exp_counts

    // fused l_aux contribution: (me_e) * (ce_e) * E, me_e = colsum_e / S
    float v = (tid < 512) ? partial_me[(size_t)tid * 64 + e] : 0.f;
    #pragma unroll
    for (int mask = 32; mask >= 1; mask >>= 1) v += __shfl_xor(v, mask);
    if (lane == 0) { if (wave < 8) red[wave] = v; else if (v != 0.f) red[0] += 0.f; }
    __syncthreads();
    if (tid == 0) {
        float ms = 0.f;
        #pragma unroll
        for (int w = 0; w < 8; ++w) ms += red[w];
        const float me = ms * (1.0f / TS);
        const float ce = (float)running * (1.0f / TS);
        atomicAdd(out, me * ce * (float)TE);
    }
}

extern "C" void kernel_launch(void* const* d_in, const int* in_sizes, int n_in,
                              void* d_out, int out_size, void* d_ws, size_t ws_size,
                              hipStream_t stream) {
    const float* x  = (const float*)d_in[0];
    const float* wg = (const float*)d_in[1];
    float* out = (float*)d_out;

    // workspace layout
    float* part       = (float*)d_ws;                        // KS*TS*TE floats (16.8 MB)
    int*   eidx       = (int*)(part + (size_t)KS * TS * TE); // TS ints
    float* gtop       = (float*)(eidx + TS);                 // TS floats
    float* partial_me = gtop + TS;                           // 512*64 floats
    int*   counts     = (int*)(partial_me + 512 * 64);       // TE ints (unused now)
    (void)counts;

    hipLaunchKernelGGL(gemm_fill, dim3(512), dim3(512), 0, stream,
                       x, wg, part, (f32x4*)out, out);
    hipLaunchKernelGGL(softmax_argmax, dim3(512), dim3(256), 0, stream,
                       part, eidx, gtop, partial_me);
    hipLaunchKernelGGL(rank_scatter_laux, dim3(64), dim3(1024), 0, stream,
                       eidx, gtop, partial_me, out);
}

// Round 6
// 166.500 us; speedup vs baseline: 1.7441x; 1.0225x over previous
//
#include <hip/hip_runtime.h>
#include <cstdint>

#define TS 8192      // tokens (S)
#define TD 4096      // model dim (D)
#define TE 64        // experts (E)
#define TCAP 128     // capacity
#define KS 16        // K-splits
#define KB (TD/KS)   // 256 k per block
#define KC 32        // k-chunk staged in LDS
#define TB 256       // tokens per block
#define NTB (TS/TB)  // 32 token-blocks

static constexpr size_t SEC = (size_t)TS * TE * TCAP;  // 67,108,864

typedef float f32x4 __attribute__((ext_vector_type(4)));   // native vec for NT builtins

// ---------------------------------------------------------------------------
// Kernel A: fp32 logits GEMM (K-split partials) FUSED with the mandatory
// 537 MB zero-fill (NT stores spread through the FMA k-loop).
// Grid 512 = 32 token-blocks x 16 K-splits; 512 threads; 8 tok x 4 exp/thread
// (2.67x fewer LDS reads per FMA than 4x4 — LDS was the co-bottleneck).
// ---------------------------------------------------------------------------
__global__ __launch_bounds__(512, 4) void gemm_fill(
    const float* __restrict__ x, const float* __restrict__ wg,
    float* __restrict__ part, f32x4* __restrict__ out4,
    float* __restrict__ out)
{
    __shared__ float xs[KC][260];   // [k][token], 256 tok + pad (16B-aligned rows)
    __shared__ float wsh[KC][68];   // [k][expert]

    const int tid = threadIdx.x;
    const int bid = blockIdx.x;
    const int tb  = bid & (NTB - 1);
    const int ks  = bid >> 5;       // 0..15
    const int tok0 = tb * TB;
    const int tx = tid & 15;        // expert group: experts tx*4..+3
    const int ty = tid >> 4;        // token group:  tokens ty*8..+7 (0..31)
    const int kq_s  = tid & 7;      // staging: k-quad 0..7
    const int row_s = tid >> 3;     // staging: row 0..63
    const long fill0 = (long)bid * 65536;
    const f32x4 z4 = {0.f, 0.f, 0.f, 0.f};

    float acc[8][4];
    #pragma unroll
    for (int i = 0; i < 8; ++i)
        #pragma unroll
        for (int j = 0; j < 4; ++j) acc[i][j] = 0.f;

    for (int it = 0; it < KB / KC; ++it) {   // 8 iterations
        const int k0 = ks * KB + it * KC;
        // stage x tile: 256 tok x 32 k, transposed -> xs[k][tok]
        #pragma unroll
        for (int r = 0; r < 4; ++r) {
            const int t = r * 64 + row_s;
            const f32x4 v = __builtin_nontemporal_load(
                reinterpret_cast<const f32x4*>(&x[(size_t)(tok0 + t) * TD + k0 + kq_s * 4]));
            xs[kq_s*4+0][t] = v.x; xs[kq_s*4+1][t] = v.y;
            xs[kq_s*4+2][t] = v.z; xs[kq_s*4+3][t] = v.w;
        }
        // stage wg tile: 64 exp x 32 k, transposed -> wsh[k][e]
        {
            const f32x4 v = *reinterpret_cast<const f32x4*>(
                &wg[(size_t)row_s * TD + k0 + kq_s * 4]);
            wsh[kq_s*4+0][row_s] = v.x; wsh[kq_s*4+1][row_s] = v.y;
            wsh[kq_s*4+2][row_s] = v.z; wsh[kq_s*4+3][row_s] = v.w;
        }
        __syncthreads();
        // micro-kernel 8 tok x 4 exp, one NT fill store every 2 k-steps
        #pragma unroll
        for (int k = 0; k < KC; ++k) {
            if ((k & 1) == 0) {
                const int j = k >> 1;
                __builtin_nontemporal_store(z4,
                    &out4[fill0 + (long)it * 8192 + j * 512 + tid]);
            }
            const f32x4 a0 = *reinterpret_cast<const f32x4*>(&xs[k][ty * 8]);
            const f32x4 a1 = *reinterpret_cast<const f32x4*>(&xs[k][ty * 8 + 4]);
            const f32x4 b  = *reinterpret_cast<const f32x4*>(&wsh[k][tx * 4]);
            acc[0][0] = fmaf(a0.x, b.x, acc[0][0]);
            acc[0][1] = fmaf(a0.x, b.y, acc[0][1]);
            acc[0][2] = fmaf(a0.x, b.z, acc[0][2]);
            acc[0][3] = fmaf(a0.x, b.w, acc[0][3]);
            acc[1][0] = fmaf(a0.y, b.x, acc[1][0]);
            acc[1][1] = fmaf(a0.y, b.y, acc[1][1]);
            acc[1][2] = fmaf(a0.y, b.z, acc[1][2]);
            acc[1][3] = fmaf(a0.y, b.w, acc[1][3]);
            acc[2][0] = fmaf(a0.z, b.x, acc[2][0]);
            acc[2][1] = fmaf(a0.z, b.y, acc[2][1]);
            acc[2][2] = fmaf(a0.z, b.z, acc[2][2]);
            acc[2][3] = fmaf(a0.z, b.w, acc[2][3]);
            acc[3][0] = fmaf(a0.w, b.x, acc[3][0]);
            acc[3][1] = fmaf(a0.w, b.y, acc[3][1]);
            acc[3][2] = fmaf(a0.w, b.z, acc[3][2]);
            acc[3][3] = fmaf(a0.w, b.w, acc[3][3]);
            acc[4][0] = fmaf(a1.x, b.x, acc[4][0]);
            acc[4][1] = fmaf(a1.x, b.y, acc[4][1]);
            acc[4][2] = fmaf(a1.x, b.z, acc[4][2]);
            acc[4][3] = fmaf(a1.x, b.w, acc[4][3]);
            acc[5][0] = fmaf(a1.y, b.x, acc[5][0]);
            acc[5][1] = fmaf(a1.y, b.y, acc[5][1]);
            acc[5][2] = fmaf(a1.y, b.z, acc[5][2]);
            acc[5][3] = fmaf(a1.y, b.w, acc[5][3]);
            acc[6][0] = fmaf(a1.z, b.x, acc[6][0]);
            acc[6][1] = fmaf(a1.z, b.y, acc[6][1]);
            acc[6][2] = fmaf(a1.z, b.z, acc[6][2]);
            acc[6][3] = fmaf(a1.z, b.w, acc[6][3]);
            acc[7][0] = fmaf(a1.w, b.x, acc[7][0]);
            acc[7][1] = fmaf(a1.w, b.y, acc[7][1]);
            acc[7][2] = fmaf(a1.w, b.z, acc[7][2]);
            acc[7][3] = fmaf(a1.w, b.w, acc[7][3]);
        }
        __syncthreads();
    }
    // tail: floats [2*SEC, 2*SEC+64] (last dispatch elem + counts slots)
    if (bid == 0 && tid < 65) out[2 * SEC + tid] = 0.f;
    // write partial logits: part[ks][tok][exp]
    #pragma unroll
    for (int i = 0; i < 8; ++i) {
        const int t = tok0 + ty * 8 + i;
        f32x4 v;
        v.x = acc[i][0]; v.y = acc[i][1]; v.z = acc[i][2]; v.w = acc[i][3];
        *reinterpret_cast<f32x4*>(&part[((size_t)ks * TS + t) * TE + tx * 4]) = v;
    }
}

// ---------------------------------------------------------------------------
// Kernel B: reduce K-split partials + softmax + argmax per token.
// 512 blocks x 256 threads; 16 tokens/block, 16 lanes per token.
// ---------------------------------------------------------------------------
__global__ __launch_bounds__(256) void softmax_argmax(
    const float* __restrict__ part, int* __restrict__ eidx,
    float* __restrict__ gtop, float* __restrict__ partial_me)
{
    __shared__ float cs[4][64];
    const int tid = threadIdx.x;
    const int tx = tid & 15;
    const int ty = tid >> 4;
    const int s = blockIdx.x * 16 + ty;

    float p[4] = {0.f, 0.f, 0.f, 0.f};
    #pragma unroll
    for (int ks = 0; ks < KS; ++ks) {
        const f32x4 v = *reinterpret_cast<const f32x4*>(
            &part[((size_t)ks * TS + s) * TE + tx * 4]);
        p[0] += v.x; p[1] += v.y; p[2] += v.z; p[3] += v.w;
    }

    float lm = fmaxf(fmaxf(p[0], p[1]), fmaxf(p[2], p[3]));
    #pragma unroll
    for (int mask = 1; mask <= 8; mask <<= 1)
        lm = fmaxf(lm, __shfl_xor(lm, mask));
    float ep[4]; float ls = 0.f;
    #pragma unroll
    for (int j = 0; j < 4; ++j) { ep[j] = __expf(p[j] - lm); ls += ep[j]; }
    #pragma unroll
    for (int mask = 1; mask <= 8; mask <<= 1)
        ls += __shfl_xor(ls, mask);
    const float invZ = 1.0f / ls;

    // argmax, lowest-index tie-break (matches jnp.argmax)
    float bv = p[0]; int bi = tx * 4;
    #pragma unroll
    for (int j = 1; j < 4; ++j)
        if (p[j] > bv) { bv = p[j]; bi = tx * 4 + j; }
    #pragma unroll
    for (int mask = 1; mask <= 8; mask <<= 1) {
        const float ov = __shfl_xor(bv, mask);
        const int   oi = __shfl_xor(bi, mask);
        if (ov > bv || (ov == bv && oi < bi)) { bv = ov; bi = oi; }
    }
    if (tx == 0) { eidx[s] = bi; gtop[s] = invZ; }

    float colsum[4];
    #pragma unroll
    for (int j = 0; j < 4; ++j) colsum[j] = ep[j] * invZ;
    #pragma unroll
    for (int j = 0; j < 4; ++j) {
        colsum[j] += __shfl_xor(colsum[j], 16);
        colsum[j] += __shfl_xor(colsum[j], 32);
    }
    const int wave = tid >> 6;
    const int lane = tid & 63;
    if (lane < 16) {
        #pragma unroll
        for (int j = 0; j < 4; ++j) cs[wave][lane * 4 + j] = colsum[j];
    }
    __syncthreads();
    if (tid < 64) {
        partial_me[(size_t)blockIdx.x * 64 + tid] =
            cs[0][tid] + cs[1][tid] + cs[2][tid] + cs[3][tid];
    }
}

// ---------------------------------------------------------------------------
// Kernel C: per-expert ordered rank + capacity + scatter + fused l_aux.
// 64 blocks x 1024 threads; all 8 token-chunks prefetched to registers.
// ---------------------------------------------------------------------------
__global__ __launch_bounds__(1024) void rank_scatter_laux(
    const int* __restrict__ eidx, const float* __restrict__ gtop,
    const float* __restrict__ partial_me, float* __restrict__ out)
{
    const int e = blockIdx.x;
    const int tid = threadIdx.x;
    const int wave = tid >> 6;      // 0..15
    const int lane = tid & 63;
    __shared__ int wave_tot[16];
    __shared__ float red[8];

    int ev[8];
    #pragma unroll
    for (int r = 0; r < 8; ++r) ev[r] = eidx[r * 1024 + tid];

    int running = 0;
    #pragma unroll
    for (int r = 0; r < 8; ++r) {
        const bool m = (ev[r] == e);
        const unsigned long long b = __ballot(m);
        if (lane == 0) wave_tot[wave] = __popcll(b);
        __syncthreads();
        int off = running;
        #pragma unroll
        for (int w = 0; w < 16; ++w) if (w < wave) off += wave_tot[w];
        const int rank = off + __popcll(b & ((1ull << lane) - 1ull));
        if (m && rank < TCAP) {
            const int s = r * 1024 + tid;
            const size_t base = 1 + ((size_t)s * TE + e) * TCAP + (size_t)rank;
            out[base] = gtop[s];        // combine_weights
            out[base + SEC] = 1.0f;     // dispatch_mask (as float)
        }
        int tot = 0;
        #pragma unroll
        for (int w = 0; w < 16; ++w) tot += wave_tot[w];
        running += tot;
        __syncthreads();
    }
    if (tid == 0) out[1 + 2 * SEC + e] = (float)running;   // exp_counts

    // fused l_aux contribution: me_e * ce_e * E via one atomicAdd per expert
    float v = (tid < 512) ? partial_me[(size_t)tid * 64 + e] : 0.f;
    #pragma unroll
    for (int mask = 32; mask >= 1; mask >>= 1) v += __shfl_xor(v, mask);
    if (lane == 0 && wave < 8) red[wave] = v;
    __syncthreads();
    if (tid == 0) {
        float ms = 0.f;
        #pragma unroll
        for (int w = 0; w < 8; ++w) ms += red[w];
        const float me = ms * (1.0f / TS);
        const float ce = (float)running * (1.0f / TS);
        atomicAdd(out, me * ce * (float)TE);
    }
}

extern "C" void kernel_launch(void* const* d_in, const int* in_sizes, int n_in,
                              void* d_out, int out_size, void* d_ws, size_t ws_size,
                              hipStream_t stream) {
    const float* x  = (const float*)d_in[0];
    const float* wg = (const float*)d_in[1];
    float* out = (float*)d_out;

    // workspace layout
    float* part       = (float*)d_ws;                        // KS*TS*TE floats (33.6 MB)
    int*   eidx       = (int*)(part + (size_t)KS * TS * TE); // TS ints
    float* gtop       = (float*)(eidx + TS);                 // TS floats
    float* partial_me = gtop + TS;                           // 512*64 floats

    hipLaunchKernelGGL(gemm_fill, dim3(512), dim3(512), 0, stream,
                       x, wg, part, (f32x4*)out, out);
    hipLaunchKernelGGL(softmax_argmax, dim3(512), dim3(256), 0, stream,
                       part, eidx, gtop, partial_me);
    hipLaunchKernelGGL(rank_scatter_laux, dim3(64), dim3(1024), 0, stream,
                       eidx, gtop, partial_me, out);
}

// Round 7
// 158.428 us; speedup vs baseline: 1.8329x; 1.0510x over previous
//
#include <hip/hip_runtime.h>
#include <cstdint>

#define TS 8192      // tokens (S)
#define TD 4096      // model dim (D)
#define TE 64        // experts (E)
#define TCAP 128     // capacity
#define KS 16        // K-splits
#define KB (TD/KS)   // 256 k per block
#define KC 32        // k-chunk staged in LDS
#define TB 256       // tokens per block
#define NTB (TS/TB)  // 32 token-blocks

static constexpr size_t SEC = (size_t)TS * TE * TCAP;  // 67,108,864

typedef float f32x4 __attribute__((ext_vector_type(4)));

// ---------------------------------------------------------------------------
// Kernel F: dedicated pure-write NT fill of the SECOND half of the output
// (f32x4 vecs [16,777,216 , 33,554,448) = floats [67.1M, 134.2M)).
// 8192 blocks x 256 thr; each block fills a contiguous 32 KB chunk.
// Pure-write kernels hit ~6.7 TB/s (rocclr fill evidence) => ~40 us.
// ---------------------------------------------------------------------------
__global__ __launch_bounds__(256) void fill_half(f32x4* __restrict__ out4)
{
    const f32x4 z = {0.f, 0.f, 0.f, 0.f};
    const long base = 16777216L;
    const long c0 = base + (long)blockIdx.x * 2048;
    #pragma unroll
    for (int j = 0; j < 8; ++j)
        __builtin_nontemporal_store(z, &out4[c0 + (long)j * 256 + threadIdx.x]);
    // remainder vecs [base+16,777,216 , base+16,777,232)
    if (blockIdx.x == 0 && threadIdx.x < 16)
        __builtin_nontemporal_store(z, &out4[base + 16777216L + threadIdx.x]);
}

// ---------------------------------------------------------------------------
// Kernel A: fp32 logits GEMM (K-split partials) + fill of the FIRST half
// (268 MB, one NT store every 4th k-step — the amount the GEMM's compute
// time can actually hide). Grid 512 = 32 token-blocks x 16 K-splits;
// 512 threads; 8 tok x 4 exp per thread.
// ---------------------------------------------------------------------------
__global__ __launch_bounds__(512, 4) void gemm_fill(
    const float* __restrict__ x, const float* __restrict__ wg,
    float* __restrict__ part, f32x4* __restrict__ out4,
    float* __restrict__ out)
{
    __shared__ float xs[KC][260];   // [k][token]
    __shared__ float wsh[KC][68];   // [k][expert]

    const int tid = threadIdx.x;
    const int bid = blockIdx.x;
    const int tb  = bid & (NTB - 1);
    const int ks  = bid >> 5;       // 0..15
    const int tok0 = tb * TB;
    const int tx = tid & 15;        // experts tx*4..+3
    const int ty = tid >> 4;        // tokens ty*8..+7
    const int kq_s  = tid & 7;
    const int row_s = tid >> 3;
    const long fill0 = (long)bid * 32768;   // half quota: 512*32768 = 16.7M vecs
    const f32x4 z4 = {0.f, 0.f, 0.f, 0.f};

    float acc[8][4];
    #pragma unroll
    for (int i = 0; i < 8; ++i)
        #pragma unroll
        for (int j = 0; j < 4; ++j) acc[i][j] = 0.f;

    for (int it = 0; it < KB / KC; ++it) {   // 8 iterations
        const int k0 = ks * KB + it * KC;
        #pragma unroll
        for (int r = 0; r < 4; ++r) {
            const int t = r * 64 + row_s;
            const f32x4 v = __builtin_nontemporal_load(
                reinterpret_cast<const f32x4*>(&x[(size_t)(tok0 + t) * TD + k0 + kq_s * 4]));
            xs[kq_s*4+0][t] = v.x; xs[kq_s*4+1][t] = v.y;
            xs[kq_s*4+2][t] = v.z; xs[kq_s*4+3][t] = v.w;
        }
        {
            const f32x4 v = *reinterpret_cast<const f32x4*>(
                &wg[(size_t)row_s * TD + k0 + kq_s * 4]);
            wsh[kq_s*4+0][row_s] = v.x; wsh[kq_s*4+1][row_s] = v.y;
            wsh[kq_s*4+2][row_s] = v.z; wsh[kq_s*4+3][row_s] = v.w;
        }
        __syncthreads();
        // micro-kernel 8 tok x 4 exp, one NT fill store every 4 k-steps
        #pragma unroll
        for (int k = 0; k < KC; ++k) {
            if ((k & 3) == 0) {
                const int j = k >> 2;   // 0..7
                __builtin_nontemporal_store(z4,
                    &out4[fill0 + (long)it * 4096 + j * 512 + tid]);
            }
            const f32x4 a0 = *reinterpret_cast<const f32x4*>(&xs[k][ty * 8]);
            const f32x4 a1 = *reinterpret_cast<const f32x4*>(&xs[k][ty * 8 + 4]);
            const f32x4 b  = *reinterpret_cast<const f32x4*>(&wsh[k][tx * 4]);
            acc[0][0] = fmaf(a0.x, b.x, acc[0][0]);
            acc[0][1] = fmaf(a0.x, b.y, acc[0][1]);
            acc[0][2] = fmaf(a0.x, b.z, acc[0][2]);
            acc[0][3] = fmaf(a0.x, b.w, acc[0][3]);
            acc[1][0] = fmaf(a0.y, b.x, acc[1][0]);
            acc[1][1] = fmaf(a0.y, b.y, acc[1][1]);
            acc[1][2] = fmaf(a0.y, b.z, acc[1][2]);
            acc[1][3] = fmaf(a0.y, b.w, acc[1][3]);
            acc[2][0] = fmaf(a0.z, b.x, acc[2][0]);
            acc[2][1] = fmaf(a0.z, b.y, acc[2][1]);
            acc[2][2] = fmaf(a0.z, b.z, acc[2][2]);
            acc[2][3] = fmaf(a0.z, b.w, acc[2][3]);
            acc[3][0] = fmaf(a0.w, b.x, acc[3][0]);
            acc[3][1] = fmaf(a0.w, b.y, acc[3][1]);
            acc[3][2] = fmaf(a0.w, b.z, acc[3][2]);
            acc[3][3] = fmaf(a0.w, b.w, acc[3][3]);
            acc[4][0] = fmaf(a1.x, b.x, acc[4][0]);
            acc[4][1] = fmaf(a1.x, b.y, acc[4][1]);
            acc[4][2] = fmaf(a1.x, b.z, acc[4][2]);
            acc[4][3] = fmaf(a1.x, b.w, acc[4][3]);
            acc[5][0] = fmaf(a1.y, b.x, acc[5][0]);
            acc[5][1] = fmaf(a1.y, b.y, acc[5][1]);
            acc[5][2] = fmaf(a1.y, b.z, acc[5][2]);
            acc[5][3] = fmaf(a1.y, b.w, acc[5][3]);
            acc[6][0] = fmaf(a1.z, b.x, acc[6][0]);
            acc[6][1] = fmaf(a1.z, b.y, acc[6][1]);
            acc[6][2] = fmaf(a1.z, b.z, acc[6][2]);
            acc[6][3] = fmaf(a1.z, b.w, acc[6][3]);
            acc[7][0] = fmaf(a1.w, b.x, acc[7][0]);
            acc[7][1] = fmaf(a1.w, b.y, acc[7][1]);
            acc[7][2] = fmaf(a1.w, b.z, acc[7][2]);
            acc[7][3] = fmaf(a1.w, b.w, acc[7][3]);
        }
        __syncthreads();
    }
    // final scalar (out_size = 2*SEC + 65; fill_half covers up to 2*SEC+64)
    if (bid == 0 && tid == 0) out[2 * SEC + 64] = 0.f;
    // write partial logits: part[ks][tok][exp]
    #pragma unroll
    for (int i = 0; i < 8; ++i) {
        const int t = tok0 + ty * 8 + i;
        f32x4 v;
        v.x = acc[i][0]; v.y = acc[i][1]; v.z = acc[i][2]; v.w = acc[i][3];
        *reinterpret_cast<f32x4*>(&part[((size_t)ks * TS + t) * TE + tx * 4]) = v;
    }
}

// ---------------------------------------------------------------------------
// Kernel B: reduce K-split partials + softmax + argmax per token.
// ---------------------------------------------------------------------------
__global__ __launch_bounds__(256) void softmax_argmax(
    const float* __restrict__ part, int* __restrict__ eidx,
    float* __restrict__ gtop, float* __restrict__ partial_me)
{
    __shared__ float cs[4][64];
    const int tid = threadIdx.x;
    const int tx = tid & 15;
    const int ty = tid >> 4;
    const int s = blockIdx.x * 16 + ty;

    float p[4] = {0.f, 0.f, 0.f, 0.f};
    #pragma unroll
    for (int ks = 0; ks < KS; ++ks) {
        const f32x4 v = *reinterpret_cast<const f32x4*>(
            &part[((size_t)ks * TS + s) * TE + tx * 4]);
        p[0] += v.x; p[1] += v.y; p[2] += v.z; p[3] += v.w;
    }

    float lm = fmaxf(fmaxf(p[0], p[1]), fmaxf(p[2], p[3]));
    #pragma unroll
    for (int mask = 1; mask <= 8; mask <<= 1)
        lm = fmaxf(lm, __shfl_xor(lm, mask));
    float ep[4]; float ls = 0.f;
    #pragma unroll
    for (int j = 0; j < 4; ++j) { ep[j] = __expf(p[j] - lm); ls += ep[j]; }
    #pragma unroll
    for (int mask = 1; mask <= 8; mask <<= 1)
        ls += __shfl_xor(ls, mask);
    const float invZ = 1.0f / ls;

    float bv = p[0]; int bi = tx * 4;
    #pragma unroll
    for (int j = 1; j < 4; ++j)
        if (p[j] > bv) { bv = p[j]; bi = tx * 4 + j; }
    #pragma unroll
    for (int mask = 1; mask <= 8; mask <<= 1) {
        const float ov = __shfl_xor(bv, mask);
        const int   oi = __shfl_xor(bi, mask);
        if (ov > bv || (ov == bv && oi < bi)) { bv = ov; bi = oi; }
    }
    if (tx == 0) { eidx[s] = bi; gtop[s] = invZ; }

    float colsum[4];
    #pragma unroll
    for (int j = 0; j < 4; ++j) colsum[j] = ep[j] * invZ;
    #pragma unroll
    for (int j = 0; j < 4; ++j) {
        colsum[j] += __shfl_xor(colsum[j], 16);
        colsum[j] += __shfl_xor(colsum[j], 32);
    }
    const int wave = tid >> 6;
    const int lane = tid & 63;
    if (lane < 16) {
        #pragma unroll
        for (int j = 0; j < 4; ++j) cs[wave][lane * 4 + j] = colsum[j];
    }
    __syncthreads();
    if (tid < 64) {
        partial_me[(size_t)blockIdx.x * 64 + tid] =
            cs[0][tid] + cs[1][tid] + cs[2][tid] + cs[3][tid];
    }
}

// ---------------------------------------------------------------------------
// Kernel C: per-expert ordered rank + capacity + scatter + fused l_aux.
// ---------------------------------------------------------------------------
__global__ __launch_bounds__(1024) void rank_scatter_laux(
    const int* __restrict__ eidx, const float* __restrict__ gtop,
    const float* __restrict__ partial_me, float* __restrict__ out)
{
    const int e = blockIdx.x;
    const int tid = threadIdx.x;
    const int wave = tid >> 6;
    const int lane = tid & 63;
    __shared__ int wave_tot[16];
    __shared__ float red[8];

    int ev[8];
    #pragma unroll
    for (int r = 0; r < 8; ++r) ev[r] = eidx[r * 1024 + tid];

    int running = 0;
    #pragma unroll
    for (int r = 0; r < 8; ++r) {
        const bool m = (ev[r] == e);
        const unsigned long long b = __ballot(m);
        if (lane == 0) wave_tot[wave] = __popcll(b);
        __syncthreads();
        int off = running;
        #pragma unroll
        for (int w = 0; w < 16; ++w) if (w < wave) off += wave_tot[w];
        const int rank = off + __popcll(b & ((1ull << lane) - 1ull));
        if (m && rank < TCAP) {
            const int s = r * 1024 + tid;
            const size_t base = 1 + ((size_t)s * TE + e) * TCAP + (size_t)rank;
            out[base] = gtop[s];        // combine_weights
            out[base + SEC] = 1.0f;     // dispatch_mask (as float)
        }
        int tot = 0;
        #pragma unroll
        for (int w = 0; w < 16; ++w) tot += wave_tot[w];
        running += tot;
        __syncthreads();
    }
    if (tid == 0) out[1 + 2 * SEC + e] = (float)running;   // exp_counts

    float v = (tid < 512) ? partial_me[(size_t)tid * 64 + e] : 0.f;
    #pragma unroll
    for (int mask = 32; mask >= 1; mask >>= 1) v += __shfl_xor(v, mask);
    if (lane == 0 && wave < 8) red[wave] = v;
    __syncthreads();
    if (tid == 0) {
        float ms = 0.f;
        #pragma unroll
        for (int w = 0; w < 8; ++w) ms += red[w];
        const float me = ms * (1.0f / TS);
        const float ce = (float)running * (1.0f / TS);
        atomicAdd(out, me * ce * (float)TE);
    }
}

extern "C" void kernel_launch(void* const* d_in, const int* in_sizes, int n_in,
                              void* d_out, int out_size, void* d_ws, size_t ws_size,
                              hipStream_t stream) {
    const float* x  = (const float*)d_in[0];
    const float* wg = (const float*)d_in[1];
    float* out = (float*)d_out;

    // workspace layout
    float* part       = (float*)d_ws;                        // KS*TS*TE floats (33.6 MB)
    int*   eidx       = (int*)(part + (size_t)KS * TS * TE); // TS ints
    float* gtop       = (float*)(eidx + TS);                 // TS floats
    float* partial_me = gtop + TS;                           // 512*64 floats

    hipLaunchKernelGGL(fill_half, dim3(8192), dim3(256), 0, stream,
                       (f32x4*)out);
    hipLaunchKernelGGL(gemm_fill, dim3(512), dim3(512), 0, stream,
                       x, wg, part, (f32x4*)out, out);
    hipLaunchKernelGGL(softmax_argmax, dim3(512), dim3(256), 0, stream,
                       part, eidx, gtop, partial_me);
    hipLaunchKernelGGL(rank_scatter_laux, dim3(64), dim3(1024), 0, stream,
                       eidx, gtop, partial_me, out);
}